// Round 12
// baseline (1849.231 us; speedup 1.0000x reference)
//
#include <hip/hip_runtime.h>
#include <hip/hip_bf16.h>
#include <cstdint>

#define D_DIM 2048
#define F_DIM 1024
#define E_NUM 64
#define K_TOP 8
#define CAP   1024

typedef __attribute__((ext_vector_type(8))) short short8;
typedef __attribute__((ext_vector_type(4))) float f32x4;

__device__ __forceinline__ uint16_t f_to_bf16(float f) {
    union { float f; uint32_t u; } v; v.f = f;
    uint32_t r = v.u + 0x7FFF + ((v.u >> 16) & 1);
    return (uint16_t)(r >> 16);
}
__device__ __forceinline__ float bf16_to_f(uint16_t u) {
    union { uint32_t u; float f; } v; v.u = ((uint32_t)u) << 16; return v.f;
}
__device__ __forceinline__ uint32_t pack2(float a, float b) {
    __hip_bfloat162 t = __float22bfloat162_rn(make_float2(a, b));
    return *reinterpret_cast<uint32_t*>(&t);
}
__device__ __forceinline__ void gload16(const void* g, void* l) {
    __builtin_amdgcn_global_load_lds(
        (const __attribute__((address_space(1))) uint32_t*)g,
        (__attribute__((address_space(3))) uint32_t*)l, 16, 0, 0);
}

// wait until <=N vector loads outstanding, then workgroup barrier
#define WAIT_BARRIER(N) asm volatile("s_waitcnt vmcnt(" #N ")\ns_barrier" ::: "memory")

// ---------------- x -> bf16 ----------------
__global__ __launch_bounds__(256) void cvtx_k(const float* __restrict__ x,
        uint16_t* __restrict__ xb, int n8) {
    int i = blockIdx.x * 256 + threadIdx.x;
    if (i >= n8) return;
    const float4* p = (const float4*)x + (size_t)i * 2;
    float4 a = p[0], b = p[1];
    uint4 o;
    o.x = pack2(a.x, a.y); o.y = pack2(a.z, a.w);
    o.z = pack2(b.x, b.y); o.w = pack2(b.z, b.w);
    ((uint4*)xb)[i] = o;
}

// ------- weight convert + transpose: src [E][R][C] f32 -> dst [E][C][R] bf16 -------
__global__ __launch_bounds__(256) void cvtw_k(const float* __restrict__ src,
        uint16_t* __restrict__ dst, int R, int C) {
    int e = blockIdx.z;
    int c0 = blockIdx.x * 64;
    int r0 = blockIdx.y * 64;
    __shared__ float ls[64][68];
    int t = threadIdx.x;
    int sr = t >> 2, sc = (t & 3) * 16;
    const float* sp = src + (size_t)e * R * C + (size_t)(r0 + sr) * C + c0 + sc;
    #pragma unroll
    for (int j = 0; j < 4; ++j) {
        float4 v = *(const float4*)(sp + j * 4);
        *(float4*)&ls[sr][sc + j * 4] = v;
    }
    __syncthreads();
    int oc = t >> 2, orr = (t & 3) * 16;
    uint16_t* dp = dst + (size_t)e * C * R + (size_t)(c0 + oc) * R + r0 + orr;
    uint4 o[2];
    uint32_t* ow = (uint32_t*)o;
    #pragma unroll
    for (int j = 0; j < 8; ++j)
        ow[j] = pack2(ls[orr + 2 * j][oc], ls[orr + 2 * j + 1][oc]);
    *(uint4*)(dp) = o[0];
    *(uint4*)(dp + 8) = o[1];
}

// ---------------- Router ----------------
__global__ __launch_bounds__(64) void router_k(const float* __restrict__ x,
        const float* __restrict__ gw, int* __restrict__ topi,
        float* __restrict__ topw) {
    int t = blockIdx.x;
    int tid = threadIdx.x;
    __shared__ float xs[D_DIM];
    __shared__ float lgs[E_NUM];
    const float* xr = x + (size_t)t * D_DIM;
    for (int d = tid; d < D_DIM; d += 64) xs[d] = xr[d];
    __syncthreads();
    const float* w = gw + (size_t)tid * D_DIM;
    float acc = 0.f;
    #pragma unroll 8
    for (int d = 0; d < D_DIM; ++d) acc = fmaf(xs[d], w[d], acc);
    lgs[tid] = acc;
    __syncthreads();
    if (tid == 0) {
        float mx = -INFINITY;
        for (int e = 0; e < E_NUM; ++e) mx = fmaxf(mx, lgs[e]);
        float se = 0.f;
        for (int e = 0; e < E_NUM; ++e) se += expf(lgs[e] - mx);
        float inv = 1.f / se;
        uint64_t used = 0;
        for (int k = 0; k < K_TOP; ++k) {
            int bi = 0; float bv = -INFINITY;
            for (int e = 0; e < E_NUM; ++e) {
                if (!((used >> e) & 1) && lgs[e] > bv) { bv = lgs[e]; bi = e; }
            }
            used |= 1ull << bi;
            topi[t * K_TOP + k] = bi;
            topw[t * K_TOP + k] = expf(bv - mx) * inv;
        }
    }
}

// ---------------- Slot assignment ----------------
__global__ void assign_k(const int* __restrict__ topi, const float* __restrict__ topw,
        int* __restrict__ cnt, int* __restrict__ rowtok, float* __restrict__ aw,
        int* __restrict__ slotof, int T) {
    int t = blockIdx.x * blockDim.x + threadIdx.x;
    if (t >= T) return;
    for (int k = 0; k < K_TOP; ++k) {
        int e = topi[t * K_TOP + k];
        int pos = atomicAdd(&cnt[e], 1);
        if (pos < CAP) {
            rowtok[e * CAP + pos] = t;
            aw[e * CAP + pos] = topw[t * K_TOP + k];
            slotof[t * K_TOP + k] = e * CAP + pos;
        } else {
            slotof[t * K_TOP + k] = -1;
        }
    }
}

// ======== Gate+Up: 128m x 64f, BK=32, ring-4 LDS, 3-deep prefetch,
//          counted vmcnt + ONE barrier per tile ========
#define GU_STAGE(B_, K0_) do {                                                \
    gload16(agp0 + (K0_), (char*)&As[B_][0] + tid * 16);                      \
    gload16(agp1 + (K0_), (char*)&As[B_][0] + (256 + tid) * 16);              \
    gload16(bgp + (K0_),  (char*)&Bg[B_][0] + tid * 16);                      \
    gload16(bup + (K0_),  (char*)&Bu[B_][0] + tid * 16);                      \
} while (0)

__global__ __launch_bounds__(256) void gateup_k(const uint16_t* __restrict__ xb,
        const uint16_t* __restrict__ wgt, const uint16_t* __restrict__ wut,
        const int* __restrict__ cnt, const int* __restrict__ rowtok,
        uint16_t* __restrict__ h) {
    int flat = blockIdx.x;
    int xcd = flat & 7;
    int idx = flat >> 3;
    int m = idx & 7;
    int sloc = idx >> 3;              // 0..127
    int strip = sloc * 8 + xcd;       // 0..1023 = e*16 + f
    int e = strip >> 4;
    int f = strip & 15;
    int m0 = m * 128;
    int ne = min(cnt[e], CAP);
    int nr = ne - m0;
    if (nr <= 0) return;
    if (nr > 128) nr = 128;
    int slot0 = e * CAP + m0;
    int fbase = f * 64;

    __shared__ __align__(16) uint16_t As[4][128 * 32];   // 4 x 8KB
    __shared__ __align__(16) uint16_t Bg[4][64 * 32];    // 4 x 4KB
    __shared__ __align__(16) uint16_t Bu[4][64 * 32];    // 4 x 4KB

    int tid = threadIdx.x;
    int l = tid & 63, wid = tid >> 6;
    int ln = l & 15, lq = l >> 4;
    int wr = wid >> 1, wc = wid & 1;

    // staging sources (inverse-swizzled oct within 32-k row: oc ^ (row&3))
    int srow = tid >> 2, soc = tid & 3;
    int tok0 = rowtok[slot0 + min(srow, nr - 1)];
    int tok1 = rowtok[slot0 + min(64 + srow, nr - 1)];
    const uint16_t* agp0 = xb + (size_t)tok0 * D_DIM + ((soc ^ (srow & 3)) * 8);
    const uint16_t* agp1 = xb + (size_t)tok1 * D_DIM + ((soc ^ ((64 + srow) & 3)) * 8);
    size_t go = ((size_t)e * F_DIM + fbase + srow) * D_DIM + ((soc ^ (srow & 3)) * 8);
    const uint16_t* bgp = wgt + go;
    const uint16_t* bup = wut + go;

    f32x4 accg[4][2], accu[4][2];
    #pragma unroll
    for (int mi = 0; mi < 4; ++mi)
        #pragma unroll
        for (int ni = 0; ni < 2; ++ni) {
            accg[mi][ni] = (f32x4){0.f, 0.f, 0.f, 0.f};
            accu[mi][ni] = (f32x4){0.f, 0.f, 0.f, 0.f};
        }

    const int NT = D_DIM / 32;        // 64
    GU_STAGE(0, 0);
    GU_STAGE(1, 32);
    GU_STAGE(2, 64);
    for (int t = 0; t < NT; ++t) {
        int cur = t & 3;
        // wait for tile t (tiles t+1,t+2 = 8 loads may stay outstanding)
        if (t + 2 < NT)       WAIT_BARRIER(8);
        else if (t + 1 < NT)  WAIT_BARRIER(4);
        else                  WAIT_BARRIER(0);
        // stage t+3 (safe: all waves finished compute(t-1) at the barrier above)
        if (t + 3 < NT) GU_STAGE((t + 3) & 3, (t + 3) * 32);
        // compute tile t
        short8 af[4], bg2[2], bu2[2];
        #pragma unroll
        for (int mi = 0; mi < 4; ++mi) {
            int row = wr * 64 + mi * 16 + ln;
            af[mi] = *(const short8*)((char*)&As[cur][0] + row * 64 + ((lq ^ (row & 3)) * 16));
        }
        #pragma unroll
        for (int ni = 0; ni < 2; ++ni) {
            int row = wc * 32 + ni * 16 + ln;
            int off = row * 64 + ((lq ^ (row & 3)) * 16);
            bg2[ni] = *(const short8*)((char*)&Bg[cur][0] + off);
            bu2[ni] = *(const short8*)((char*)&Bu[cur][0] + off);
        }
        #pragma unroll
        for (int mi = 0; mi < 4; ++mi)
            #pragma unroll
            for (int ni = 0; ni < 2; ++ni) {
                accg[mi][ni] = __builtin_amdgcn_mfma_f32_16x16x32_bf16(af[mi], bg2[ni], accg[mi][ni], 0, 0, 0);
                accu[mi][ni] = __builtin_amdgcn_mfma_f32_16x16x32_bf16(af[mi], bu2[ni], accu[mi][ni], 0, 0, 0);
            }
    }

    #pragma unroll
    for (int mi = 0; mi < 4; ++mi) {
        #pragma unroll
        for (int j = 0; j < 4; ++j) {
            int row = wr * 64 + mi * 16 + lq * 4 + j;
            if (row < nr) {
                size_t hb = (size_t)(slot0 + row) * F_DIM + fbase + wc * 32 + ln;
                #pragma unroll
                for (int ni = 0; ni < 2; ++ni) {
                    float g = accg[mi][ni][j], u = accu[mi][ni][j];
                    h[hb + ni * 16] = f_to_bf16(g / (1.f + __expf(-g)) * u);
                }
            }
        }
    }
}

// ======== Down: 128m x 64d, BK=32, ring-4, 3-deep prefetch; writes weighted y ========
#define DN_STAGE(B_, K0_) do {                                                \
    gload16(agp0 + (K0_), (char*)&As[B_][0] + tid * 16);                      \
    gload16(agp1 + (K0_), (char*)&As[B_][0] + (256 + tid) * 16);              \
    gload16(bp + (K0_),   (char*)&Bs[B_][0] + tid * 16);                      \
} while (0)

__global__ __launch_bounds__(256) void down_k(const uint16_t* __restrict__ h,
        const uint16_t* __restrict__ wdt, const int* __restrict__ cnt,
        const float* __restrict__ aw, uint16_t* __restrict__ y) {
    int flat = blockIdx.x;
    int xcd = flat & 7;
    int idx = flat >> 3;
    int m = idx & 7;
    int sloc = idx >> 3;              // 0..255
    int strip = sloc * 8 + xcd;       // 0..2047 = e*32 + dt
    int e = strip >> 5;
    int dt = strip & 31;
    int m0 = m * 128;
    int ne = min(cnt[e], CAP);
    int nr = ne - m0;
    if (nr <= 0) return;
    if (nr > 128) nr = 128;
    int slot0 = e * CAP + m0;
    int dbase = dt * 64;

    __shared__ __align__(16) uint16_t As[4][128 * 32];   // 4 x 8KB
    __shared__ __align__(16) uint16_t Bs[4][64 * 32];    // 4 x 4KB

    int tid = threadIdx.x;
    int l = tid & 63, wid = tid >> 6;
    int ln = l & 15, lq = l >> 4;
    int wr = wid >> 1, wc = wid & 1;

    int srow = tid >> 2, soc = tid & 3;
    const uint16_t* agp0 = h + (size_t)(slot0 + min(srow, nr - 1)) * F_DIM
                         + ((soc ^ (srow & 3)) * 8);
    const uint16_t* agp1 = h + (size_t)(slot0 + min(64 + srow, nr - 1)) * F_DIM
                         + ((soc ^ ((64 + srow) & 3)) * 8);
    const uint16_t* bp = wdt + ((size_t)e * D_DIM + dbase + srow) * F_DIM
                       + ((soc ^ (srow & 3)) * 8);

    f32x4 acc[4][2];
    #pragma unroll
    for (int mi = 0; mi < 4; ++mi)
        #pragma unroll
        for (int ni = 0; ni < 2; ++ni)
            acc[mi][ni] = (f32x4){0.f, 0.f, 0.f, 0.f};

    const int NT = F_DIM / 32;        // 32
    DN_STAGE(0, 0);
    DN_STAGE(1, 32);
    DN_STAGE(2, 64);
    for (int t = 0; t < NT; ++t) {
        int cur = t & 3;
        if (t + 2 < NT)       WAIT_BARRIER(6);
        else if (t + 1 < NT)  WAIT_BARRIER(3);
        else                  WAIT_BARRIER(0);
        if (t + 3 < NT) DN_STAGE((t + 3) & 3, (t + 3) * 32);
        short8 af[4], bf2[2];
        #pragma unroll
        for (int mi = 0; mi < 4; ++mi) {
            int row = wr * 64 + mi * 16 + ln;
            af[mi] = *(const short8*)((char*)&As[cur][0] + row * 64 + ((lq ^ (row & 3)) * 16));
        }
        #pragma unroll
        for (int ni = 0; ni < 2; ++ni) {
            int row = wc * 32 + ni * 16 + ln;
            bf2[ni] = *(const short8*)((char*)&Bs[cur][0] + row * 64 + ((lq ^ (row & 3)) * 16));
        }
        #pragma unroll
        for (int mi = 0; mi < 4; ++mi)
            #pragma unroll
            for (int ni = 0; ni < 2; ++ni)
                acc[mi][ni] = __builtin_amdgcn_mfma_f32_16x16x32_bf16(af[mi], bf2[ni], acc[mi][ni], 0, 0, 0);
    }

    #pragma unroll
    for (int mi = 0; mi < 4; ++mi) {
        #pragma unroll
        for (int j = 0; j < 4; ++j) {
            int row = wr * 64 + mi * 16 + lq * 4 + j;
            if (row < nr) {
                int slot = slot0 + row;
                float wgt = aw[slot];
                uint16_t* yrow = y + (size_t)slot * D_DIM + dbase + wc * 32 + ln;
                #pragma unroll
                for (int ni = 0; ni < 2; ++ni)
                    yrow[ni * 16] = f_to_bf16(acc[mi][ni][j] * wgt);
            }
        }
    }
}

// ---------------- Combine: out[t] = sum_k y[slot(t,k)] ----------------
__global__ __launch_bounds__(256) void combine_k(const uint16_t* __restrict__ y,
        const int* __restrict__ slotof, float* __restrict__ out) {
    int t = blockIdx.x;
    int tid = threadIdx.x;
    int sl[K_TOP];
    #pragma unroll
    for (int k = 0; k < K_TOP; ++k) sl[k] = slotof[t * K_TOP + k];
    float acc[8];
    #pragma unroll
    for (int j = 0; j < 8; ++j) acc[j] = 0.f;
    #pragma unroll
    for (int k = 0; k < K_TOP; ++k) {
        if (sl[k] >= 0) {
            const uint16_t* row = y + (size_t)sl[k] * D_DIM;
            #pragma unroll
            for (int j = 0; j < 8; ++j)
                acc[j] += bf16_to_f(row[tid + j * 256]);
        }
    }
    float* orow = out + (size_t)t * D_DIM;
    #pragma unroll
    for (int j = 0; j < 8; ++j)
        orow[tid + j * 256] = acc[j];
}

extern "C" void kernel_launch(void* const* d_in, const int* in_sizes, int n_in,
                              void* d_out, int out_size, void* d_ws, size_t ws_size,
                              hipStream_t stream) {
    const float* x  = (const float*)d_in[0];
    const float* gw = (const float*)d_in[1];
    const float* wg = (const float*)d_in[2];
    const float* wu = (const float*)d_in[3];
    const float* wd = (const float*)d_in[4];
    float* out = (float*)d_out;
    int T = in_sizes[0] / D_DIM;

    char* ws = (char*)d_ws;
    size_t off = 0;
    auto alloc = [&](size_t bytes) -> void* {
        void* p = ws + off;
        off = (off + bytes + 255) & ~(size_t)255;
        return p;
    };
    int*      cnt    = (int*)     alloc(E_NUM * sizeof(int));
    int*      topi   = (int*)     alloc((size_t)T * K_TOP * sizeof(int));
    float*    topw   = (float*)   alloc((size_t)T * K_TOP * sizeof(float));
    int*      rowtok = (int*)     alloc((size_t)E_NUM * CAP * sizeof(int));
    float*    aw     = (float*)   alloc((size_t)E_NUM * CAP * sizeof(float));
    int*      slotof = (int*)     alloc((size_t)T * K_TOP * sizeof(int));
    uint16_t* xb     = (uint16_t*)alloc((size_t)T * D_DIM * sizeof(uint16_t));
    uint16_t* h      = (uint16_t*)alloc((size_t)E_NUM * CAP * F_DIM * sizeof(uint16_t));
    uint16_t* wgt    = (uint16_t*)alloc((size_t)E_NUM * D_DIM * F_DIM * sizeof(uint16_t));
    uint16_t* wut    = (uint16_t*)alloc((size_t)E_NUM * D_DIM * F_DIM * sizeof(uint16_t));
    uint16_t* wdt    = wgt;   // alias: gateup consumed wgt before wd conversion
    uint16_t* y      = wut;   // alias: gateup consumed wut before down writes y

    hipMemsetAsync(cnt, 0, E_NUM * sizeof(int), stream);

    int n8 = T * D_DIM / 8;
    cvtx_k<<<(n8 + 255) / 256, 256, 0, stream>>>(x, xb, n8);
    router_k<<<T, 64, 0, stream>>>(x, gw, topi, topw);
    assign_k<<<(T + 255) / 256, 256, 0, stream>>>(topi, topw, cnt, rowtok, aw, slotof, T);
    cvtw_k<<<dim3(F_DIM / 64, D_DIM / 64, E_NUM), 256, 0, stream>>>(wg, wgt, D_DIM, F_DIM);
    cvtw_k<<<dim3(F_DIM / 64, D_DIM / 64, E_NUM), 256, 0, stream>>>(wu, wut, D_DIM, F_DIM);
    gateup_k<<<E_NUM * 16 * 8, 256, 0, stream>>>(xb, wgt, wut, cnt, rowtok, h);
    cvtw_k<<<dim3(D_DIM / 64, F_DIM / 64, E_NUM), 256, 0, stream>>>(wd, wdt, F_DIM, D_DIM);
    down_k<<<E_NUM * 32 * 8, 256, 0, stream>>>(h, wdt, cnt, aw, y);
    combine_k<<<T, 256, 0, stream>>>(y, slotof, out);
}

// Round 13
// 1574.966 us; speedup vs baseline: 1.1741x; 1.1741x over previous
//
#include <hip/hip_runtime.h>
#include <hip/hip_bf16.h>
#include <cstdint>

#define D_DIM 2048
#define F_DIM 1024
#define E_NUM 64
#define K_TOP 8
#define CAP   1024

typedef __attribute__((ext_vector_type(8))) short short8;
typedef __attribute__((ext_vector_type(4))) float f32x4;

__device__ __forceinline__ uint16_t f_to_bf16(float f) {
    union { float f; uint32_t u; } v; v.f = f;
    uint32_t r = v.u + 0x7FFF + ((v.u >> 16) & 1);
    return (uint16_t)(r >> 16);
}
__device__ __forceinline__ float bf16_to_f(uint16_t u) {
    union { uint32_t u; float f; } v; v.u = ((uint32_t)u) << 16; return v.f;
}
__device__ __forceinline__ uint32_t pack2(float a, float b) {
    __hip_bfloat162 t = __float22bfloat162_rn(make_float2(a, b));
    return *reinterpret_cast<uint32_t*>(&t);
}
__device__ __forceinline__ void gload16(const void* g, void* l) {
    __builtin_amdgcn_global_load_lds(
        (const __attribute__((address_space(1))) uint32_t*)g,
        (__attribute__((address_space(3))) uint32_t*)l, 16, 0, 0);
}

// ---------------- x -> bf16 ----------------
__global__ __launch_bounds__(256) void cvtx_k(const float* __restrict__ x,
        uint16_t* __restrict__ xb, int n8) {
    int i = blockIdx.x * 256 + threadIdx.x;
    if (i >= n8) return;
    const float4* p = (const float4*)x + (size_t)i * 2;
    float4 a = p[0], b = p[1];
    uint4 o;
    o.x = pack2(a.x, a.y); o.y = pack2(a.z, a.w);
    o.z = pack2(b.x, b.y); o.w = pack2(b.z, b.w);
    ((uint4*)xb)[i] = o;
}

// ------- weight convert + transpose: src [E][R][C] f32 -> dst [E][C][R] bf16 -------
// LDS column-XOR (bit 4) so transpose reads are 2-way (free) instead of 4-way.
__global__ __launch_bounds__(256) void cvtw_k(const float* __restrict__ src,
        uint16_t* __restrict__ dst, int R, int C) {
    int e = blockIdx.z;
    int c0 = blockIdx.x * 64;
    int r0 = blockIdx.y * 64;
    __shared__ float ls[64][68];
    int t = threadIdx.x;
    int sr = t >> 2, sc = (t & 3) * 16;
    int skey = ((sr >> 4) & 1) << 4;
    const float* sp = src + (size_t)e * R * C + (size_t)(r0 + sr) * C + c0 + sc;
    #pragma unroll
    for (int j = 0; j < 4; ++j) {
        float4 v = *(const float4*)(sp + j * 4);
        *(float4*)&ls[sr][(sc + j * 4) ^ skey] = v;
    }
    __syncthreads();
    int oc = t >> 2, orr = (t & 3) * 16;
    int rkey = ((orr >> 4) & 1) << 4;
    int occ = oc ^ rkey;
    uint16_t* dp = dst + (size_t)e * C * R + (size_t)(c0 + oc) * R + r0 + orr;
    uint4 o[2];
    uint32_t* ow = (uint32_t*)o;
    #pragma unroll
    for (int j = 0; j < 8; ++j)
        ow[j] = pack2(ls[orr + 2 * j][occ], ls[orr + 2 * j + 1][occ]);
    *(uint4*)(dp) = o[0];
    *(uint4*)(dp + 8) = o[1];
}

// ---------------- Router ----------------
__global__ __launch_bounds__(64) void router_k(const float* __restrict__ x,
        const float* __restrict__ gw, int* __restrict__ topi,
        float* __restrict__ topw) {
    int t = blockIdx.x;
    int tid = threadIdx.x;
    __shared__ float xs[D_DIM];
    __shared__ float lgs[E_NUM];
    const float* xr = x + (size_t)t * D_DIM;
    for (int d = tid; d < D_DIM; d += 64) xs[d] = xr[d];
    __syncthreads();
    const float* w = gw + (size_t)tid * D_DIM;
    float acc = 0.f;
    #pragma unroll 8
    for (int d = 0; d < D_DIM; ++d) acc = fmaf(xs[d], w[d], acc);
    lgs[tid] = acc;
    __syncthreads();
    if (tid == 0) {
        float mx = -INFINITY;
        for (int e = 0; e < E_NUM; ++e) mx = fmaxf(mx, lgs[e]);
        float se = 0.f;
        for (int e = 0; e < E_NUM; ++e) se += expf(lgs[e] - mx);
        float inv = 1.f / se;
        uint64_t used = 0;
        for (int k = 0; k < K_TOP; ++k) {
            int bi = 0; float bv = -INFINITY;
            for (int e = 0; e < E_NUM; ++e) {
                if (!((used >> e) & 1) && lgs[e] > bv) { bv = lgs[e]; bi = e; }
            }
            used |= 1ull << bi;
            topi[t * K_TOP + k] = bi;
            topw[t * K_TOP + k] = expf(bv - mx) * inv;
        }
    }
}

// ---------------- Slot assignment ----------------
__global__ void assign_k(const int* __restrict__ topi, const float* __restrict__ topw,
        int* __restrict__ cnt, int* __restrict__ rowtok, float* __restrict__ aw,
        int* __restrict__ slotof, int T) {
    int t = blockIdx.x * blockDim.x + threadIdx.x;
    if (t >= T) return;
    for (int k = 0; k < K_TOP; ++k) {
        int e = topi[t * K_TOP + k];
        int pos = atomicAdd(&cnt[e], 1);
        if (pos < CAP) {
            rowtok[e * CAP + pos] = t;
            aw[e * CAP + pos] = topw[t * K_TOP + k];
            slotof[t * K_TOP + k] = e * CAP + pos;
        } else {
            slotof[t * K_TOP + k] = -1;
        }
    }
}

// ======== Gate+Up: 128m x 64f, BK=64, global_load_lds + XOR swizzle ========
// (r9 structure verbatim: 32KB single-buffer, drain barrier per tile)
__global__ __launch_bounds__(256) void gateup_k(const uint16_t* __restrict__ xb,
        const uint16_t* __restrict__ wgt, const uint16_t* __restrict__ wut,
        const int* __restrict__ cnt, const int* __restrict__ rowtok,
        uint16_t* __restrict__ h) {
    int flat = blockIdx.x;
    int xcd = flat & 7;
    int idx = flat >> 3;
    int m = idx & 7;
    int sloc = idx >> 3;              // 0..127
    int strip = sloc * 8 + xcd;       // 0..1023 = e*16 + f
    int e = strip >> 4;
    int f = strip & 15;
    int m0 = m * 128;
    int ne = min(cnt[e], CAP);
    int nr = ne - m0;
    if (nr <= 0) return;
    if (nr > 128) nr = 128;
    int slot0 = e * CAP + m0;
    int fbase = f * 64;

    __shared__ __align__(16) uint16_t As[128 * 64];   // 16KB, rows 128B
    __shared__ __align__(16) uint16_t Bg[64 * 64];    // 8KB
    __shared__ __align__(16) uint16_t Bu[64 * 64];    // 8KB

    int tid = threadIdx.x;
    int l = tid & 63, wid = tid >> 6;
    int ln = l & 15, lq = l >> 4;
    int wr = wid >> 1, wc = wid & 1;

    const uint16_t* agp[4];
    #pragma unroll
    for (int i = 0; i < 4; ++i) {
        int c = i * 256 + tid;
        int row = c >> 3, col = c & 7;
        int tok = rowtok[slot0 + min(row, nr - 1)];
        agp[i] = xb + (size_t)tok * D_DIM + ((col ^ (row & 7)) * 8);
    }
    const uint16_t *bgp[2], *bup[2];
    #pragma unroll
    for (int i = 0; i < 2; ++i) {
        int c = i * 256 + tid;
        int row = c >> 3, col = c & 7;
        size_t go = ((size_t)e * F_DIM + fbase + row) * D_DIM + ((col ^ (row & 7)) * 8);
        bgp[i] = wgt + go;
        bup[i] = wut + go;
    }

    f32x4 accg[4][2], accu[4][2];
    #pragma unroll
    for (int mi = 0; mi < 4; ++mi)
        #pragma unroll
        for (int ni = 0; ni < 2; ++ni) {
            accg[mi][ni] = (f32x4){0.f, 0.f, 0.f, 0.f};
            accu[mi][ni] = (f32x4){0.f, 0.f, 0.f, 0.f};
        }

    const int NT = D_DIM / 64;        // 32
    for (int t = 0; t < NT; ++t) {
        int k0 = t * 64;
        #pragma unroll
        for (int i = 0; i < 4; ++i)
            gload16(agp[i] + k0, (char*)As + (i * 256 + wid * 64) * 16);
        #pragma unroll
        for (int i = 0; i < 2; ++i) {
            gload16(bgp[i] + k0, (char*)Bg + (i * 256 + wid * 64) * 16);
            gload16(bup[i] + k0, (char*)Bu + (i * 256 + wid * 64) * 16);
        }
        __syncthreads();
        #pragma unroll
        for (int kk = 0; kk < 2; ++kk) {
            short8 af[4], bg[2], bu[2];
            #pragma unroll
            for (int mi = 0; mi < 4; ++mi) {
                int row = wr * 64 + mi * 16 + ln;
                af[mi] = *(const short8*)((char*)As + row * 128 + (((kk * 4 + lq) ^ (row & 7)) * 16));
            }
            #pragma unroll
            for (int ni = 0; ni < 2; ++ni) {
                int row = wc * 32 + ni * 16 + ln;
                int off = row * 128 + (((kk * 4 + lq) ^ (row & 7)) * 16);
                bg[ni] = *(const short8*)((char*)Bg + off);
                bu[ni] = *(const short8*)((char*)Bu + off);
            }
            #pragma unroll
            for (int mi = 0; mi < 4; ++mi)
                #pragma unroll
                for (int ni = 0; ni < 2; ++ni) {
                    accg[mi][ni] = __builtin_amdgcn_mfma_f32_16x16x32_bf16(af[mi], bg[ni], accg[mi][ni], 0, 0, 0);
                    accu[mi][ni] = __builtin_amdgcn_mfma_f32_16x16x32_bf16(af[mi], bu[ni], accu[mi][ni], 0, 0, 0);
                }
        }
        __syncthreads();
    }

    #pragma unroll
    for (int mi = 0; mi < 4; ++mi) {
        #pragma unroll
        for (int j = 0; j < 4; ++j) {
            int row = wr * 64 + mi * 16 + lq * 4 + j;
            if (row < nr) {
                size_t hb = (size_t)(slot0 + row) * F_DIM + fbase + wc * 32 + ln;
                #pragma unroll
                for (int ni = 0; ni < 2; ++ni) {
                    float g = accg[mi][ni][j], u = accu[mi][ni][j];
                    h[hb + ni * 16] = f_to_bf16(g / (1.f + __expf(-g)) * u);
                }
            }
        }
    }
}

// ======== Down: 128m x 128d, BK=64, gload16 + XOR swizzle, 32KB LDS ========
// Wider d-tile amortizes A staging 2x; writes pre-weighted bf16 y rows.
__global__ __launch_bounds__(256) void down_k(const uint16_t* __restrict__ h,
        const uint16_t* __restrict__ wdt, const int* __restrict__ cnt,
        const float* __restrict__ aw, uint16_t* __restrict__ y) {
    int flat = blockIdx.x;
    int xcd = flat & 7;
    int idx = flat >> 3;
    int m = idx & 7;
    int sloc = idx >> 3;              // 0..127
    int strip = sloc * 8 + xcd;       // 0..1023 = e*16 + dt
    int e = strip >> 4;
    int dt = strip & 15;
    int m0 = m * 128;
    int ne = min(cnt[e], CAP);
    int nr = ne - m0;
    if (nr <= 0) return;
    if (nr > 128) nr = 128;
    int slot0 = e * CAP + m0;
    int dbase = dt * 128;

    __shared__ __align__(16) uint16_t As[128 * 64];   // 16KB
    __shared__ __align__(16) uint16_t Bs[128 * 64];   // 16KB

    int tid = threadIdx.x;
    int l = tid & 63, wid = tid >> 6;
    int ln = l & 15, lq = l >> 4;
    int wr = wid >> 1, wc = wid & 1;

    const uint16_t* agp[4];
    #pragma unroll
    for (int i = 0; i < 4; ++i) {
        int c = i * 256 + tid;
        int row = c >> 3, col = c & 7;
        agp[i] = h + (size_t)(slot0 + min(row, nr - 1)) * F_DIM + ((col ^ (row & 7)) * 8);
    }
    const uint16_t* bp[4];
    #pragma unroll
    for (int i = 0; i < 4; ++i) {
        int c = i * 256 + tid;
        int row = c >> 3, col = c & 7;
        bp[i] = wdt + ((size_t)e * D_DIM + dbase + row) * F_DIM + ((col ^ (row & 7)) * 8);
    }

    f32x4 acc[4][4];
    #pragma unroll
    for (int mi = 0; mi < 4; ++mi)
        #pragma unroll
        for (int ni = 0; ni < 4; ++ni)
            acc[mi][ni] = (f32x4){0.f, 0.f, 0.f, 0.f};

    const int NT = F_DIM / 64;        // 16
    for (int t = 0; t < NT; ++t) {
        int k0 = t * 64;
        #pragma unroll
        for (int i = 0; i < 4; ++i)
            gload16(agp[i] + k0, (char*)As + (i * 256 + wid * 64) * 16);
        #pragma unroll
        for (int i = 0; i < 4; ++i)
            gload16(bp[i] + k0, (char*)Bs + (i * 256 + wid * 64) * 16);
        __syncthreads();
        #pragma unroll
        for (int kk = 0; kk < 2; ++kk) {
            short8 af[4], bf[4];
            #pragma unroll
            for (int mi = 0; mi < 4; ++mi) {
                int row = wr * 64 + mi * 16 + ln;
                af[mi] = *(const short8*)((char*)As + row * 128 + (((kk * 4 + lq) ^ (row & 7)) * 16));
            }
            #pragma unroll
            for (int ni = 0; ni < 4; ++ni) {
                int row = wc * 64 + ni * 16 + ln;
                bf[ni] = *(const short8*)((char*)Bs + row * 128 + (((kk * 4 + lq) ^ (row & 7)) * 16));
            }
            #pragma unroll
            for (int mi = 0; mi < 4; ++mi)
                #pragma unroll
                for (int ni = 0; ni < 4; ++ni)
                    acc[mi][ni] = __builtin_amdgcn_mfma_f32_16x16x32_bf16(af[mi], bf[ni], acc[mi][ni], 0, 0, 0);
        }
        __syncthreads();
    }

    #pragma unroll
    for (int mi = 0; mi < 4; ++mi) {
        #pragma unroll
        for (int j = 0; j < 4; ++j) {
            int row = wr * 64 + mi * 16 + lq * 4 + j;
            if (row < nr) {
                int slot = slot0 + row;
                float wgt = aw[slot];
                uint16_t* yrow = y + (size_t)slot * D_DIM + dbase + wc * 64 + ln;
                #pragma unroll
                for (int ni = 0; ni < 4; ++ni)
                    yrow[ni * 16] = f_to_bf16(acc[mi][ni][j] * wgt);
            }
        }
    }
}

// ---------------- Combine: out[t] = sum_k y[slot(t,k)] ----------------
__global__ __launch_bounds__(256) void combine_k(const uint16_t* __restrict__ y,
        const int* __restrict__ slotof, float* __restrict__ out) {
    int t = blockIdx.x;
    int tid = threadIdx.x;
    int sl[K_TOP];
    #pragma unroll
    for (int k = 0; k < K_TOP; ++k) sl[k] = slotof[t * K_TOP + k];
    float acc[8];
    #pragma unroll
    for (int j = 0; j < 8; ++j) acc[j] = 0.f;
    #pragma unroll
    for (int k = 0; k < K_TOP; ++k) {
        if (sl[k] >= 0) {
            const uint16_t* row = y + (size_t)sl[k] * D_DIM;
            #pragma unroll
            for (int j = 0; j < 8; ++j)
                acc[j] += bf16_to_f(row[tid + j * 256]);
        }
    }
    float* orow = out + (size_t)t * D_DIM;
    #pragma unroll
    for (int j = 0; j < 8; ++j)
        orow[tid + j * 256] = acc[j];
}

extern "C" void kernel_launch(void* const* d_in, const int* in_sizes, int n_in,
                              void* d_out, int out_size, void* d_ws, size_t ws_size,
                              hipStream_t stream) {
    const float* x  = (const float*)d_in[0];
    const float* gw = (const float*)d_in[1];
    const float* wg = (const float*)d_in[2];
    const float* wu = (const float*)d_in[3];
    const float* wd = (const float*)d_in[4];
    float* out = (float*)d_out;
    int T = in_sizes[0] / D_DIM;

    char* ws = (char*)d_ws;
    size_t off = 0;
    auto alloc = [&](size_t bytes) -> void* {
        void* p = ws + off;
        off = (off + bytes + 255) & ~(size_t)255;
        return p;
    };
    int*      cnt    = (int*)     alloc(E_NUM * sizeof(int));
    int*      topi   = (int*)     alloc((size_t)T * K_TOP * sizeof(int));
    float*    topw   = (float*)   alloc((size_t)T * K_TOP * sizeof(float));
    int*      rowtok = (int*)     alloc((size_t)E_NUM * CAP * sizeof(int));
    float*    aw     = (float*)   alloc((size_t)E_NUM * CAP * sizeof(float));
    int*      slotof = (int*)     alloc((size_t)T * K_TOP * sizeof(int));
    uint16_t* xb     = (uint16_t*)alloc((size_t)T * D_DIM * sizeof(uint16_t));
    uint16_t* h      = (uint16_t*)alloc((size_t)E_NUM * CAP * F_DIM * sizeof(uint16_t));
    uint16_t* wgt    = (uint16_t*)alloc((size_t)E_NUM * D_DIM * F_DIM * sizeof(uint16_t));
    uint16_t* wut    = (uint16_t*)alloc((size_t)E_NUM * D_DIM * F_DIM * sizeof(uint16_t));
    uint16_t* wdt    = wgt;   // alias: gateup consumed wgt before wd conversion
    uint16_t* y      = wut;   // alias: gateup consumed wut before down writes y

    hipMemsetAsync(cnt, 0, E_NUM * sizeof(int), stream);

    int n8 = T * D_DIM / 8;
    cvtx_k<<<(n8 + 255) / 256, 256, 0, stream>>>(x, xb, n8);
    router_k<<<T, 64, 0, stream>>>(x, gw, topi, topw);
    assign_k<<<(T + 255) / 256, 256, 0, stream>>>(topi, topw, cnt, rowtok, aw, slotof, T);
    cvtw_k<<<dim3(F_DIM / 64, D_DIM / 64, E_NUM), 256, 0, stream>>>(wg, wgt, D_DIM, F_DIM);
    cvtw_k<<<dim3(F_DIM / 64, D_DIM / 64, E_NUM), 256, 0, stream>>>(wu, wut, D_DIM, F_DIM);
    gateup_k<<<E_NUM * 16 * 8, 256, 0, stream>>>(xb, wgt, wut, cnt, rowtok, h);
    cvtw_k<<<dim3(D_DIM / 64, F_DIM / 64, E_NUM), 256, 0, stream>>>(wd, wdt, F_DIM, D_DIM);
    down_k<<<E_NUM * 16 * 8, 256, 0, stream>>>(h, wdt, cnt, aw, y);
    combine_k<<<T, 256, 0, stream>>>(y, slotof, out);
}